// Round 13
// baseline (427.102 us; speedup 1.0000x reference)
//
#include <hip/hip_runtime.h>
#include <math.h>

// Problem constants
#define B_   8
#define C_   128
#define C2_  256
#define H_   128
#define W_   128
#define HW_  16384
#define CR_  32
#define EPS_ 1e-5f
#define NS_  32     // n-splits for sim partial sums

typedef _Float16 f16;
typedef f16 f16x8 __attribute__((ext_vector_type(8)));
typedef f16 f16x4 __attribute__((ext_vector_type(4)));
typedef float f32x4 __attribute__((ext_vector_type(4)));

// ---------------------------------------------------------------------------
// Kernel 1: prep — avg partials + NHWC f16 repack + conv-weight repack
//           + zero-page init (for conv halo glds).
// ---------------------------------------------------------------------------
__global__ __launch_bounds__(256) void prep_kernel(
    const float* __restrict__ x1, const float* __restrict__ x2,
    const float* __restrict__ conv_w,
    float* __restrict__ avgp, f16* __restrict__ xs, f16* __restrict__ wt,
    float* __restrict__ zp)
{
    __shared__ f16 T[W_ * 136];
    __shared__ float part[C2_];
    int h = blockIdx.x, b = blockIdx.y;
    int tid = threadIdx.x;
    if (h == 0 && b == 0 && tid < 128) zp[tid] = 0.f;   // 512 B zero page
    f16* out = xs + ((size_t)b * H_ + h) * W_ * C2_;
    for (int p = 0; p < 2; ++p) {
        const float* src = p ? x2 : x1;
        __syncthreads();
        for (int idx = tid; idx < C_ * 32; idx += 256) {
            int c = idx >> 5, w4 = (idx & 31) << 2;
            const float4 v = *(const float4*)&src[(((size_t)b * C_ + c) * H_ + h) * W_ + w4];
            float s = v.x + v.y + v.z + v.w;
            s += __shfl_xor(s, 1, 64);  s += __shfl_xor(s, 2, 64);
            s += __shfl_xor(s, 4, 64);  s += __shfl_xor(s, 8, 64);
            s += __shfl_xor(s, 16, 64);
            if ((tid & 31) == 0) part[p * C_ + c] = s;
            int cs = c ^ (8 * ((idx & 31) & 15));
            T[(w4 + 0) * 136 + cs] = (f16)v.x;
            T[(w4 + 1) * 136 + cs] = (f16)v.y;
            T[(w4 + 2) * 136 + cs] = (f16)v.z;
            T[(w4 + 3) * 136 + cs] = (f16)v.w;
        }
        __syncthreads();
        for (int u = tid; u < W_ * 16; u += 256) {
            int w = u >> 4, o = u & 15;
            f16x8 v = *(const f16x8*)&T[w * 136 + ((o * 8) ^ (8 * ((w >> 2) & 15)))];
            *(f16x8*)&out[w * C2_ + p * C_ + o * 8] = v;
        }
    }
    __syncthreads();
    avgp[((size_t)h * B_ + b) * C2_ + tid] = part[tid];
    // fused weight repack: wt[cc][t][co][32ci], 288 elems per block, exact cover
    {
        int base = (b * H_ + h) * 288;
        for (int i = tid; i < 288; i += 256) {
            int idx = base + i;
            int ci = idx & 31;
            int co = (idx >> 5) & 127;
            int tt = idx >> 12;
            int cc = tt / 9, t = tt - cc * 9;
            wt[idx] = (f16)conv_w[((size_t)co * C2_ + cc * 32 + ci) * 9 + t];
        }
    }
}

// ---------------------------------------------------------------------------
// Kernel 2: SE MLP, one block per batch (8 blocks)
// ---------------------------------------------------------------------------
__global__ __launch_bounds__(256) void se_mlp_kernel(
    const float* __restrict__ avgp, const float* __restrict__ w1,
    const float* __restrict__ w2, float* __restrict__ se)
{
    int b = blockIdx.x;
    __shared__ float s_avg[C2_];
    __shared__ float s_h[CR_];
    float s = 0.f;
    for (int h = 0; h < H_; ++h)
        s += avgp[((size_t)h * B_ + b) * C2_ + threadIdx.x];
    s_avg[threadIdx.x] = s * (1.f / (float)HW_);
    __syncthreads();
    {
        int j = threadIdx.x >> 3, sub = threadIdx.x & 7;   // 8 threads per output
        float a = 0.f;
        #pragma unroll 8
        for (int k = sub * 32; k < sub * 32 + 32; ++k) a += s_avg[k] * w1[j * C2_ + k];
        a += __shfl_xor(a, 1, 64); a += __shfl_xor(a, 2, 64); a += __shfl_xor(a, 4, 64);
        if (sub == 0) s_h[j] = fmaxf(a, 0.f);
    }
    __syncthreads();
    float o = 0.f;
    #pragma unroll
    for (int j = 0; j < CR_; ++j) o += s_h[j] * w2[threadIdx.x * CR_ + j];
    se[b * C2_ + threadIdx.x] = 1.f / (1.f + expf(-o));
}

// ---------------------------------------------------------------------------
// Kernel 3: conv implicit GEMM, v4.
// v3 post-mortem: LDS-pipe-bound (reads 69us + writes 11 + conflicts 27 of
// 131us; MfmaUtil 25% = bare MFMA time). v4 attacks LDS traffic:
//  - wave tile 64co x 64n (acc 4x4=64 regs): 8 reads / 16 MFMA (2x intensity)
//  - global_load_lds staging: NO ds_writes, NO staging regs
//  - half-K (16ci) phases + 16x16x16 MFMA -> LDS/block 35.6 KB ->
//    4 blocks x 4 waves = 16 waves/CU at <=128 regs
//  - XOR granule swizzle (source-permuted, linear LDS dest) -> <=2-way (free)
//  - SE gate folded into A-operand (W*se == conv identity)
//  - zero-page source for halo lanes (glds cannot conditionally zero)
// Block = 2h x 64co x 128n; waves orow(2) x nh(2); grid (H/2, 2, B) = 1024.
// ---------------------------------------------------------------------------
#define WH_F16  9216             // 9*64*16
#define XH_F16  8320             // 4*130*16
#define SMEM_BYTES 35584         // (9216+8320+256)*2

__device__ __forceinline__ void gload16(const f16* g, f16* l) {
    __builtin_amdgcn_global_load_lds(
        (const __attribute__((address_space(1))) void*)(g),
        (__attribute__((address_space(3))) void*)(l), 16, 0, 0);
}

__global__ __launch_bounds__(256, 4) void conv_mfma_big(
    const f16* __restrict__ xs, const f16* __restrict__ wt,
    const float* __restrict__ se, const f16* __restrict__ zp,
    const float* __restrict__ bn_gamma, const float* __restrict__ bn_beta,
    const float* __restrict__ bn_mean, const float* __restrict__ bn_var,
    f16* __restrict__ yh, f16* __restrict__ yt)
{
    extern __shared__ __align__(16) f16 smem[];
    f16* Ws  = smem;                       // 9216 f16
    f16* Xs  = smem + WH_F16;              // 8320 f16
    f16* seh = smem + WH_F16 + XH_F16;     // 256 f16

    int h0 = blockIdx.x * 2, cy = blockIdx.y, b = blockIdx.z;
    int tid = threadIdx.x;
    int wave = tid >> 6, lane = tid & 63;
    int orow = wave >> 1, nh = wave & 1;
    int lr = lane & 15, kg = lane >> 4;
    const f16* xsb = xs + (size_t)b * ((size_t)H_ * W_ * C2_);

    seh[tid] = (f16)se[b * C2_ + tid];     // visible after phase-0 barrier

    f32x4 acc[4][4];
    #pragma unroll
    for (int i = 0; i < 4; ++i)
        #pragma unroll
        for (int j = 0; j < 4; ++j)
            #pragma unroll
            for (int r = 0; r < 4; ++r) acc[i][j][r] = 0.f;

    for (int ph = 0; ph < 16; ++ph) {
        if (ph) __syncthreads();           // readers of previous phase done
        int cc = ph >> 1, cio = (ph & 1) * 16;
        // stage W half-chunk: 1152 16B slots, linear LDS, swizzled source
        #pragma unroll
        for (int k = 0; k < 5; ++k) {
            int u = k * 256 + tid;
            if (u < 1152) {
                int cell = u >> 1, p = u & 1;
                int t = cell >> 6, co_l = cell & 63;
                int hsrc = p ^ ((co_l ^ (co_l >> 2)) & 1);
                gload16(wt + (((size_t)(cc * 9 + t) * 128 + cy * 64 + co_l) << 5)
                           + cio + (hsrc << 3),
                        Ws + u * 8);
            }
        }
        // stage X half-chunk: 1040 slots; halo lanes read the zero page
        #pragma unroll
        for (int k = 0; k < 5; ++k) {
            int u = k * 256 + tid;
            if (u < 1040) {
                int cell = u >> 1, p = u & 1;
                int r = cell / 130, col = cell - r * 130;
                int hsrc = p ^ ((col ^ (col >> 2)) & 1);
                int gh = h0 - 1 + r, gw = col - 1;
                const f16* src = ((unsigned)gh < (unsigned)H_ && (unsigned)gw < (unsigned)W_)
                    ? xsb + (((size_t)gh << 7) + (size_t)gw) * C2_ + ph * 16 + (hsrc << 3)
                    : zp;
                gload16(src, Xs + u * 8);
            }
        }
        __syncthreads();                   // drains vmcnt: staged data ready
        f16x4 sv = *(const f16x4*)&seh[ph * 16 + kg * 4];
        #pragma unroll
        for (int t = 0; t < 9; ++t) {
            const int dh = t / 3, dw = t % 3;
            const int rr = orow + dh;
            f16x4 bf[4];
            #pragma unroll
            for (int j = 0; j < 4; ++j) {
                int col = nh * 64 + j * 16 + lr + dw;
                int pos = kg ^ (((col ^ (col >> 2)) & 1) << 1);
                bf[j] = *(const f16x4*)&Xs[(rr * 130 + col) * 16 + pos * 4];
            }
            #pragma unroll
            for (int i2 = 0; i2 < 4; ++i2) {
                int co_l = i2 * 16 + lr;
                int pos = kg ^ (((co_l ^ (co_l >> 2)) & 1) << 1);
                f16x4 af = *(const f16x4*)&Ws[(t * 64 + co_l) * 16 + pos * 4];
                af = af * sv;              // SE gate folded into A operand
                #pragma unroll
                for (int j = 0; j < 4; ++j)
                    acc[i2][j] = __builtin_amdgcn_mfma_f32_16x16x16f16(
                        af, bf[j], acc[i2][j], 0, 0, 0);
            }
        }
    }
    // epilogue: BN+ReLU; D layout col(lane&15)=n, row=kg*4+r(+16*i2)=c.
    int h = h0 + orow;
    f16x4 tvv[4][4];
    #pragma unroll
    for (int i2 = 0; i2 < 4; ++i2) {
        int cb = cy * 64 + i2 * 16 + kg * 4;
        float inv[4], add[4];
        #pragma unroll
        for (int r = 0; r < 4; ++r) {
            int c = cb + r;
            inv[r] = bn_gamma[c] * rsqrtf(bn_var[c] + EPS_);
            add[r] = bn_beta[c] - bn_mean[c] * inv[r];
        }
        #pragma unroll
        for (int j = 0; j < 4; ++j) {
            int n = nh * 64 + j * 16 + lr;
            f16x4 tv;
            #pragma unroll
            for (int r = 0; r < 4; ++r) {
                float v = fmaxf(acc[i2][j][r] * inv[r] + add[r], 0.f);
                tv[r] = (f16)v;
                yh[((size_t)b * C_ + cb + r) * HW_ + h * W_ + n] = (f16)v;
            }
            tvv[i2][j] = tv;
        }
    }
    // yt via 2-pass LDS transpose (reuse smem: 128*72 f16 = 18432 B <= 35 KB)
    f16* T = smem;
    for (int ro = 0; ro < 2; ++ro) {
        __syncthreads();
        if (orow == ro) {
            #pragma unroll
            for (int i2 = 0; i2 < 4; ++i2)
                #pragma unroll
                for (int j = 0; j < 4; ++j)
                    *(f16x4*)&T[(nh * 64 + j * 16 + lr) * 72 + i2 * 16 + kg * 4] = tvv[i2][j];
        }
        __syncthreads();
        for (int u = tid; u < 1024; u += 256) {
            int n = u >> 3, o8 = u & 7;
            *(f16x8*)&yt[((size_t)b * HW_ + (h0 + ro) * W_ + n) * C_ + cy * 64 + o8 * 8] =
                *(const f16x8*)&T[n * 72 + o8 * 8];
        }
    }
}

// ---------------------------------------------------------------------------
// Kernel 4: sim partials via MFMA (unchanged)
// ---------------------------------------------------------------------------
__global__ __launch_bounds__(512) void sim_mfma_kernel(
    const f16* __restrict__ yh, float* __restrict__ simp)
{
    int ns = blockIdx.x, b = blockIdx.y;
    int tid = threadIdx.x, wave = tid >> 6, lane = tid & 63;
    int wm = wave >> 2, wn = wave & 3;
    int lr = lane & 15, kg = lane >> 4;
    const f16* Y = yh + (size_t)b * C_ * HW_;
    int n0 = ns * (HW_ / NS_);

    f32x4 acc[4][2];
    #pragma unroll
    for (int i = 0; i < 4; ++i)
        #pragma unroll
        for (int j = 0; j < 2; ++j)
            #pragma unroll
            for (int r = 0; r < 4; ++r) acc[i][j][r] = 0.f;

    for (int kk = 0; kk < 16; ++kk) {
        int k = n0 + kk * 32 + kg * 8;
        f16x8 af[4], bf[2];
        #pragma unroll
        for (int i = 0; i < 4; ++i)
            af[i] = *(const f16x8*)&Y[(size_t)(wm * 64 + i * 16 + lr) * HW_ + k];
        #pragma unroll
        for (int j = 0; j < 2; ++j)
            bf[j] = *(const f16x8*)&Y[(size_t)(wn * 32 + j * 16 + lr) * HW_ + k];
        #pragma unroll
        for (int i = 0; i < 4; ++i)
            #pragma unroll
            for (int j = 0; j < 2; ++j)
                acc[i][j] = __builtin_amdgcn_mfma_f32_16x16x32_f16(af[i], bf[j], acc[i][j], 0, 0, 0);
    }
    float* dst = simp + (size_t)(ns * B_ + b) * C_ * C_;
    #pragma unroll
    for (int i = 0; i < 4; ++i)
        #pragma unroll
        for (int j = 0; j < 2; ++j)
            #pragma unroll
            for (int r = 0; r < 4; ++r)
                dst[(wm * 64 + i * 16 + kg * 4 + r) * C_ + wn * 32 + j * 16 + lr] = acc[i][j][r];
}

// ---------------------------------------------------------------------------
// Kernel 5: reduce partials + softmax(-sim) -> Ph fp16 (unchanged)
// ---------------------------------------------------------------------------
__global__ __launch_bounds__(128) void softmax_kernel(
    const float* __restrict__ simp, f16* __restrict__ Ph)
{
    int bc = blockIdx.x;
    int b = bc / C_;
    int d = threadIdx.x;
    float s = 0.f;
    for (int ns = 0; ns < NS_; ++ns)
        s += simp[((size_t)(ns * B_ + b) * C_ + (bc % C_)) * C_ + d];
    float v = -s;
    float m = v;
    #pragma unroll
    for (int off = 32; off > 0; off >>= 1) m = fmaxf(m, __shfl_xor(m, off, 64));
    __shared__ float sm[2], ss[2];
    int wid = threadIdx.x >> 6;
    if ((threadIdx.x & 63) == 0) sm[wid] = m;
    __syncthreads();
    m = fmaxf(sm[0], sm[1]);
    float p = expf(v - m);
    float sum = p;
    #pragma unroll
    for (int off = 32; off > 0; off >>= 1) sum += __shfl_xor(sum, off, 64);
    if ((threadIdx.x & 63) == 0) ss[wid] = sum;
    __syncthreads();
    sum = ss[0] + ss[1];
    Ph[(size_t)bc * C_ + d] = (f16)(p / sum);
}

// ---------------------------------------------------------------------------
// Kernel 6: feat = P @ y via MFMA; out = gamma*feat + y (unchanged)
// ---------------------------------------------------------------------------
__global__ __launch_bounds__(256) void feat_mfma_kernel(
    const f16* __restrict__ Ph, const f16* __restrict__ yt,
    const f16* __restrict__ yh,
    const float* __restrict__ gamma, float* __restrict__ out)
{
    int nt = blockIdx.x, b = blockIdx.y;
    int tid = threadIdx.x, wave = tid >> 6, lane = tid & 63;
    int wm = wave >> 1, wn = wave & 1;
    int lr = lane & 15, kg = lane >> 4;
    int n0 = nt * 128;
    const f16* Pb = Ph + (size_t)b * C_ * C_;
    const f16* Yt = yt + (size_t)b * HW_ * C_;

    f32x4 acc[4][4];
    #pragma unroll
    for (int i = 0; i < 4; ++i)
        #pragma unroll
        for (int j = 0; j < 4; ++j)
            #pragma unroll
            for (int r = 0; r < 4; ++r) acc[i][j][r] = 0.f;

    #pragma unroll
    for (int kk = 0; kk < 4; ++kk) {
        int k = kk * 32 + kg * 8;
        f16x8 af[4], bf[4];
        #pragma unroll
        for (int i = 0; i < 4; ++i)
            af[i] = *(const f16x8*)&Pb[(wm * 64 + i * 16 + lr) * C_ + k];
        #pragma unroll
        for (int j = 0; j < 4; ++j)
            bf[j] = *(const f16x8*)&Yt[(size_t)(n0 + wn * 64 + j * 16 + lr) * C_ + k];
        #pragma unroll
        for (int i = 0; i < 4; ++i)
            #pragma unroll
            for (int j = 0; j < 4; ++j)
                acc[i][j] = __builtin_amdgcn_mfma_f32_16x16x32_f16(af[i], bf[j], acc[i][j], 0, 0, 0);
    }
    float g = gamma[0];
    #pragma unroll
    for (int i = 0; i < 4; ++i) {
        int cb = wm * 64 + i * 16 + kg * 4;
        #pragma unroll
        for (int j = 0; j < 4; ++j) {
            int n = n0 + wn * 64 + j * 16 + lr;
            #pragma unroll
            for (int r = 0; r < 4; ++r) {
                float res = (float)yh[((size_t)b * C_ + cb + r) * HW_ + n];
                out[((size_t)b * C_ + cb + r) * HW_ + n] = g * acc[i][j][r] + res;
            }
        }
    }
}

// ---------------------------------------------------------------------------
extern "C" void kernel_launch(void* const* d_in, const int* in_sizes, int n_in,
                              void* d_out, int out_size, void* d_ws, size_t ws_size,
                              hipStream_t stream)
{
    const float* x1       = (const float*)d_in[0];
    const float* x2       = (const float*)d_in[1];
    const float* se_w1    = (const float*)d_in[2];
    const float* se_w2    = (const float*)d_in[3];
    const float* conv_w   = (const float*)d_in[4];
    const float* bn_gamma = (const float*)d_in[5];
    const float* bn_beta  = (const float*)d_in[6];
    const float* bn_mean  = (const float*)d_in[7];
    const float* bn_var   = (const float*)d_in[8];
    const float* gamma    = (const float*)d_in[9];
    float* out = (float*)d_out;

    // Workspace layout — total 135,266,304 B (proven footprint)
    char* ws = (char*)d_ws;
    float* zp   = (float*)(ws);                      //       0 +   512 B (zero page)
    float* se   = (float*)(ws + 8192);               //    8192 +     8 KB
    f16*   Ph   = (f16*)  (ws + 16384);              //   16384 +   256 KB
    f16*   wt   = (f16*)  (ws + 278528);             //  278528 +   576 KB
    f16*   xs   = (f16*)  (ws + 1048576);            // 1 MB    +    64 MB
    float* simp = (float*)(ws + 1048576);            // aliases xs (post-conv)
    f16*   yh   = (f16*)  (ws + 68157440);           //         +    32 MB
    float* avgp = (float*)(ws + 68157440);           // aliases yh (pre-conv), 1 MB
    f16*   yt   = (f16*)  (ws + 101711872);          //         +    32 MB

    prep_kernel<<<dim3(H_, B_), 256, 0, stream>>>(x1, x2, conv_w, avgp, xs, wt, zp);
    se_mlp_kernel<<<dim3(B_), 256, 0, stream>>>(avgp, se_w1, se_w2, se);

    hipFuncSetAttribute((const void*)conv_mfma_big,
        hipFuncAttributeMaxDynamicSharedMemorySize, SMEM_BYTES);
    conv_mfma_big<<<dim3(H_ / 2, 2, B_), 256, SMEM_BYTES, stream>>>(
        xs, wt, se, (const f16*)zp, bn_gamma, bn_beta, bn_mean, bn_var, yh, yt);

    sim_mfma_kernel<<<dim3(NS_, B_), 512, 0, stream>>>(yh, simp);
    softmax_kernel<<<dim3(B_ * C_), 128, 0, stream>>>(simp, Ph);
    feat_mfma_kernel<<<dim3(HW_ / 128, B_), 256, 0, stream>>>(Ph, yt, yh, gamma, out);
}

// Round 16
// 352.866 us; speedup vs baseline: 1.2104x; 1.2104x over previous
//
#include <hip/hip_runtime.h>
#include <math.h>

// Problem constants
#define B_   8
#define C_   128
#define C2_  256
#define H_   128
#define W_   128
#define HW_  16384
#define CR_  32
#define EPS_ 1e-5f
#define NS_  32     // n-splits for sim partial sums

typedef _Float16 f16;
typedef f16 f16x8 __attribute__((ext_vector_type(8)));
typedef f16 f16x4 __attribute__((ext_vector_type(4)));
typedef float f32x4 __attribute__((ext_vector_type(4)));

// ---------------------------------------------------------------------------
// Kernel 1: prep — avg partials + chunk-major xs repack [b][cc][h][w][32ci]
//           + conv-weight repack + zero-page init.
// Chunk-major xs makes conv's per-chunk stage reads fully contiguous 64-B
// cells (v4 fetched strided 16-B slices: FETCH 324 MB, HBM-bound).
// ---------------------------------------------------------------------------
__global__ __launch_bounds__(256) void prep_kernel(
    const float* __restrict__ x1, const float* __restrict__ x2,
    const float* __restrict__ conv_w,
    float* __restrict__ avgp, f16* __restrict__ xs, f16* __restrict__ wt,
    float* __restrict__ zp)
{
    __shared__ f16 T[W_ * 136];
    __shared__ float part[C2_];
    int h = blockIdx.x, b = blockIdx.y;
    int tid = threadIdx.x;
    if (h == 0 && b == 0 && tid < 128) zp[tid] = 0.f;   // 512 B zero page
    f16* xb = xs + (size_t)b * ((size_t)8 * HW_ * 32);
    for (int p = 0; p < 2; ++p) {
        const float* src = p ? x2 : x1;
        __syncthreads();
        for (int idx = tid; idx < C_ * 32; idx += 256) {
            int c = idx >> 5, w4 = (idx & 31) << 2;
            const float4 v = *(const float4*)&src[(((size_t)b * C_ + c) * H_ + h) * W_ + w4];
            float s = v.x + v.y + v.z + v.w;
            s += __shfl_xor(s, 1, 64);  s += __shfl_xor(s, 2, 64);
            s += __shfl_xor(s, 4, 64);  s += __shfl_xor(s, 8, 64);
            s += __shfl_xor(s, 16, 64);
            if ((tid & 31) == 0) part[p * C_ + c] = s;
            int cs = c ^ (8 * ((idx & 31) & 15));
            T[(w4 + 0) * 136 + cs] = (f16)v.x;
            T[(w4 + 1) * 136 + cs] = (f16)v.y;
            T[(w4 + 2) * 136 + cs] = (f16)v.z;
            T[(w4 + 3) * 136 + cs] = (f16)v.w;
        }
        __syncthreads();
        for (int u = tid; u < W_ * 16; u += 256) {
            int w = u >> 4, o = u & 15;
            f16x8 v = *(const f16x8*)&T[w * 136 + ((o * 8) ^ (8 * ((w >> 2) & 15)))];
            int ci = p * C_ + o * 8;
            *(f16x8*)&xb[(((size_t)(ci >> 5) * H_ + h) * W_ + w) * 32 + (ci & 31)] = v;
        }
    }
    __syncthreads();
    avgp[((size_t)h * B_ + b) * C2_ + tid] = part[tid];
    // fused weight repack: wt[cc][t][co][32ci], 288 elems per block, exact cover
    {
        int base = (b * H_ + h) * 288;
        for (int i = tid; i < 288; i += 256) {
            int idx = base + i;
            int ci = idx & 31;
            int co = (idx >> 5) & 127;
            int tt = idx >> 12;
            int cc = tt / 9, t = tt - cc * 9;
            wt[idx] = (f16)conv_w[((size_t)co * C2_ + cc * 32 + ci) * 9 + t];
        }
    }
}

// ---------------------------------------------------------------------------
// Kernel 2: SE MLP, one block per batch (8 blocks)
// ---------------------------------------------------------------------------
__global__ __launch_bounds__(256) void se_mlp_kernel(
    const float* __restrict__ avgp, const float* __restrict__ w1,
    const float* __restrict__ w2, float* __restrict__ se)
{
    int b = blockIdx.x;
    __shared__ float s_avg[C2_];
    __shared__ float s_h[CR_];
    float s = 0.f;
    for (int h = 0; h < H_; ++h)
        s += avgp[((size_t)h * B_ + b) * C2_ + threadIdx.x];
    s_avg[threadIdx.x] = s * (1.f / (float)HW_);
    __syncthreads();
    {
        int j = threadIdx.x >> 3, sub = threadIdx.x & 7;   // 8 threads per output
        float a = 0.f;
        #pragma unroll 8
        for (int k = sub * 32; k < sub * 32 + 32; ++k) a += s_avg[k] * w1[j * C2_ + k];
        a += __shfl_xor(a, 1, 64); a += __shfl_xor(a, 2, 64); a += __shfl_xor(a, 4, 64);
        if (sub == 0) s_h[j] = fmaxf(a, 0.f);
    }
    __syncthreads();
    float o = 0.f;
    #pragma unroll
    for (int j = 0; j < CR_; ++j) o += s_h[j] * w2[threadIdx.x * CR_ + j];
    se[b * C2_ + threadIdx.x] = 1.f / (1.f + expf(-o));
}

// ---------------------------------------------------------------------------
// Kernel 3: conv implicit GEMM, v5.
// v4 post-mortem: (a) 16x16x16 MFMA = half rate (66us floor); (b) half-K
// strided fetch -> 324 MB FETCH, HBM-bound at 166us. v5:
//  - 16x16x32 MFMA restored, K=32 chunks (8 phases)
//  - chunk-major xs: stage reads contiguous 64-B cells (full cache lines)
//  - [row][64B] LDS layout + b128 reads at row*64+kg*16: uniform bank load,
//    conflict-free with NO pad/swizzle, glds-linear-compatible
//  - glds staging (no ds_writes, no staging regs), SE folded into A operand
//  - LDS 70.7 KB -> 2 independent blocks/CU: one block computes while the
//    other drains its stage barrier (fixes R0's single-block lockstep)
// Block = 2h x 64co x 128n, 4 waves (orow 2 x nh 2); grid (2, H/2, B).
// ---------------------------------------------------------------------------
#define WC_F16  18432            // 9*64*32
#define XC_F16  16640            // 4*130*32
#define SMEM_BYTES 70656         // (18432+16640+256)*2

__device__ __forceinline__ void gload16(const f16* g, f16* l) {
    __builtin_amdgcn_global_load_lds(
        (const __attribute__((address_space(1))) void*)(g),
        (__attribute__((address_space(3))) void*)(l), 16, 0, 0);
}

__global__ __launch_bounds__(256, 2) void conv_mfma_big(
    const f16* __restrict__ xs, const f16* __restrict__ wt,
    const float* __restrict__ se, const f16* __restrict__ zp,
    const float* __restrict__ bn_gamma, const float* __restrict__ bn_beta,
    const float* __restrict__ bn_mean, const float* __restrict__ bn_var,
    f16* __restrict__ yh, f16* __restrict__ yt)
{
    extern __shared__ __align__(16) f16 smem[];
    f16* Ws  = smem;                       // 18432 f16
    f16* Xs  = smem + WC_F16;              // 16640 f16
    f16* seh = smem + WC_F16 + XC_F16;     // 256 f16

    int cy = blockIdx.x, h0 = blockIdx.y * 2, b = blockIdx.z;
    int tid = threadIdx.x;
    int wave = tid >> 6, lane = tid & 63;
    int orow = wave >> 1, nh = wave & 1;
    int lr = lane & 15, kg = lane >> 4;

    seh[tid] = (f16)se[b * C2_ + tid];     // ordered by the stage barrier

    f32x4 acc[4][4];
    #pragma unroll
    for (int i = 0; i < 4; ++i)
        #pragma unroll
        for (int j = 0; j < 4; ++j)
            #pragma unroll
            for (int r = 0; r < 4; ++r) acc[i][j][r] = 0.f;

    for (int cc = 0; cc < 8; ++cc) {
        if (cc) __syncthreads();           // readers of previous chunk done
        // stage W chunk: 9t x 64co x 32ci = 2304 16-B granules, linear
        const f16* wsrc = wt + ((size_t)(cc * 9) * 128 + cy * 64) * 32;
        #pragma unroll
        for (int k = 0; k < 9; ++k) {
            int u = k * 256 + tid;
            int row = u >> 2, g = u & 3;          // row = t*64 + co_l
            int t = row >> 6, col = row & 63;
            gload16(wsrc + (((size_t)t * 128 + col) << 5) + (g << 3),
                    Ws + u * 8);
        }
        // stage X chunk: 4 rows x 130 cols x 32ci = 2080 granules; halo -> zp
        const f16* xsc = xs + ((size_t)b * 8 + cc) * ((size_t)HW_ * 32);
        #pragma unroll
        for (int k = 0; k < 9; ++k) {
            int u = k * 256 + tid;
            if (u < 2080) {
                int cell = u >> 2, g = u & 3;
                int r = cell / 130, col = cell - r * 130;
                int gh = h0 - 1 + r, gw = col - 1;
                const f16* src = ((unsigned)gh < (unsigned)H_ && (unsigned)gw < (unsigned)W_)
                    ? xsc + (((size_t)gh * W_ + gw) << 5) + (g << 3)
                    : zp;
                gload16(src, Xs + u * 8);
            }
        }
        __syncthreads();                   // drains vmcnt: staged data ready
        f16x8 sv = *(const f16x8*)&seh[cc * 32 + kg * 8];
        #pragma unroll
        for (int t = 0; t < 9; ++t) {
            const int dh = t / 3, dw = t % 3;
            const int rr = orow + dh;
            f16x8 bf[4];
            #pragma unroll
            for (int j = 0; j < 4; ++j)
                bf[j] = *(const f16x8*)&Xs[((rr * 130 + nh * 64 + j * 16 + lr + dw) << 5) + kg * 8];
            #pragma unroll
            for (int i2 = 0; i2 < 4; ++i2) {
                f16x8 af = *(const f16x8*)&Ws[((t * 64 + i2 * 16 + lr) << 5) + kg * 8];
                af = af * sv;              // SE gate folded into A operand (ci-wise)
                #pragma unroll
                for (int j = 0; j < 4; ++j)
                    acc[i2][j] = __builtin_amdgcn_mfma_f32_16x16x32_f16(
                        af, bf[j], acc[i2][j], 0, 0, 0);
            }
        }
    }
    // epilogue: BN+ReLU; D layout col(lane&15)=n, row=kg*4+r(+16*i2)=c.
    int h = h0 + orow;
    f16x4 tvv[4][4];
    #pragma unroll
    for (int i2 = 0; i2 < 4; ++i2) {
        int cb = cy * 64 + i2 * 16 + kg * 4;
        float inv[4], add[4];
        #pragma unroll
        for (int r = 0; r < 4; ++r) {
            int c = cb + r;
            inv[r] = bn_gamma[c] * rsqrtf(bn_var[c] + EPS_);
            add[r] = bn_beta[c] - bn_mean[c] * inv[r];
        }
        #pragma unroll
        for (int j = 0; j < 4; ++j) {
            int n = nh * 64 + j * 16 + lr;
            f16x4 tv;
            #pragma unroll
            for (int r = 0; r < 4; ++r) {
                float v = fmaxf(acc[i2][j][r] * inv[r] + add[r], 0.f);
                tv[r] = (f16)v;
                yh[((size_t)b * C_ + cb + r) * HW_ + h * W_ + n] = (f16)v;
            }
            tvv[i2][j] = tv;
        }
    }
    // yt via 2-pass LDS transpose (reuse smem: 128*72 f16 = 9216 <= 35328)
    f16* T = smem;
    for (int ro = 0; ro < 2; ++ro) {
        __syncthreads();
        if (orow == ro) {
            #pragma unroll
            for (int i2 = 0; i2 < 4; ++i2)
                #pragma unroll
                for (int j = 0; j < 4; ++j)
                    *(f16x4*)&T[(nh * 64 + j * 16 + lr) * 72 + i2 * 16 + kg * 4] = tvv[i2][j];
        }
        __syncthreads();
        for (int u = tid; u < 1024; u += 256) {
            int n = u >> 3, o8 = u & 7;
            *(f16x8*)&yt[((size_t)b * HW_ + (h0 + ro) * W_ + n) * C_ + cy * 64 + o8 * 8] =
                *(const f16x8*)&T[n * 72 + o8 * 8];
        }
    }
}

// ---------------------------------------------------------------------------
// Kernel 4: sim partials via MFMA (unchanged)
// ---------------------------------------------------------------------------
__global__ __launch_bounds__(512) void sim_mfma_kernel(
    const f16* __restrict__ yh, float* __restrict__ simp)
{
    int ns = blockIdx.x, b = blockIdx.y;
    int tid = threadIdx.x, wave = tid >> 6, lane = tid & 63;
    int wm = wave >> 2, wn = wave & 3;
    int lr = lane & 15, kg = lane >> 4;
    const f16* Y = yh + (size_t)b * C_ * HW_;
    int n0 = ns * (HW_ / NS_);

    f32x4 acc[4][2];
    #pragma unroll
    for (int i = 0; i < 4; ++i)
        #pragma unroll
        for (int j = 0; j < 2; ++j)
            #pragma unroll
            for (int r = 0; r < 4; ++r) acc[i][j][r] = 0.f;

    for (int kk = 0; kk < 16; ++kk) {
        int k = n0 + kk * 32 + kg * 8;
        f16x8 af[4], bf[2];
        #pragma unroll
        for (int i = 0; i < 4; ++i)
            af[i] = *(const f16x8*)&Y[(size_t)(wm * 64 + i * 16 + lr) * HW_ + k];
        #pragma unroll
        for (int j = 0; j < 2; ++j)
            bf[j] = *(const f16x8*)&Y[(size_t)(wn * 32 + j * 16 + lr) * HW_ + k];
        #pragma unroll
        for (int i = 0; i < 4; ++i)
            #pragma unroll
            for (int j = 0; j < 2; ++j)
                acc[i][j] = __builtin_amdgcn_mfma_f32_16x16x32_f16(af[i], bf[j], acc[i][j], 0, 0, 0);
    }
    float* dst = simp + (size_t)(ns * B_ + b) * C_ * C_;
    #pragma unroll
    for (int i = 0; i < 4; ++i)
        #pragma unroll
        for (int j = 0; j < 2; ++j)
            #pragma unroll
            for (int r = 0; r < 4; ++r)
                dst[(wm * 64 + i * 16 + kg * 4 + r) * C_ + wn * 32 + j * 16 + lr] = acc[i][j][r];
}

// ---------------------------------------------------------------------------
// Kernel 5: reduce partials + softmax(-sim) -> Ph fp16 (unchanged)
// ---------------------------------------------------------------------------
__global__ __launch_bounds__(128) void softmax_kernel(
    const float* __restrict__ simp, f16* __restrict__ Ph)
{
    int bc = blockIdx.x;
    int b = bc / C_;
    int d = threadIdx.x;
    float s = 0.f;
    for (int ns = 0; ns < NS_; ++ns)
        s += simp[((size_t)(ns * B_ + b) * C_ + (bc % C_)) * C_ + d];
    float v = -s;
    float m = v;
    #pragma unroll
    for (int off = 32; off > 0; off >>= 1) m = fmaxf(m, __shfl_xor(m, off, 64));
    __shared__ float sm[2], ss[2];
    int wid = threadIdx.x >> 6;
    if ((threadIdx.x & 63) == 0) sm[wid] = m;
    __syncthreads();
    m = fmaxf(sm[0], sm[1]);
    float p = expf(v - m);
    float sum = p;
    #pragma unroll
    for (int off = 32; off > 0; off >>= 1) sum += __shfl_xor(sum, off, 64);
    if ((threadIdx.x & 63) == 0) ss[wid] = sum;
    __syncthreads();
    sum = ss[0] + ss[1];
    Ph[(size_t)bc * C_ + d] = (f16)(p / sum);
}

// ---------------------------------------------------------------------------
// Kernel 6: feat = P @ y via MFMA; out = gamma*feat + y (unchanged)
// ---------------------------------------------------------------------------
__global__ __launch_bounds__(256) void feat_mfma_kernel(
    const f16* __restrict__ Ph, const f16* __restrict__ yt,
    const f16* __restrict__ yh,
    const float* __restrict__ gamma, float* __restrict__ out)
{
    int nt = blockIdx.x, b = blockIdx.y;
    int tid = threadIdx.x, wave = tid >> 6, lane = tid & 63;
    int wm = wave >> 1, wn = wave & 1;
    int lr = lane & 15, kg = lane >> 4;
    int n0 = nt * 128;
    const f16* Pb = Ph + (size_t)b * C_ * C_;
    const f16* Yt = yt + (size_t)b * HW_ * C_;

    f32x4 acc[4][4];
    #pragma unroll
    for (int i = 0; i < 4; ++i)
        #pragma unroll
        for (int j = 0; j < 4; ++j)
            #pragma unroll
            for (int r = 0; r < 4; ++r) acc[i][j][r] = 0.f;

    #pragma unroll
    for (int kk = 0; kk < 4; ++kk) {
        int k = kk * 32 + kg * 8;
        f16x8 af[4], bf[4];
        #pragma unroll
        for (int i = 0; i < 4; ++i)
            af[i] = *(const f16x8*)&Pb[(wm * 64 + i * 16 + lr) * C_ + k];
        #pragma unroll
        for (int j = 0; j < 4; ++j)
            bf[j] = *(const f16x8*)&Yt[(size_t)(n0 + wn * 64 + j * 16 + lr) * C_ + k];
        #pragma unroll
        for (int i = 0; i < 4; ++i)
            #pragma unroll
            for (int j = 0; j < 4; ++j)
                acc[i][j] = __builtin_amdgcn_mfma_f32_16x16x32_f16(af[i], bf[j], acc[i][j], 0, 0, 0);
    }
    float g = gamma[0];
    #pragma unroll
    for (int i = 0; i < 4; ++i) {
        int cb = wm * 64 + i * 16 + kg * 4;
        #pragma unroll
        for (int j = 0; j < 4; ++j) {
            int n = n0 + wn * 64 + j * 16 + lr;
            #pragma unroll
            for (int r = 0; r < 4; ++r) {
                float res = (float)yh[((size_t)b * C_ + cb + r) * HW_ + n];
                out[((size_t)b * C_ + cb + r) * HW_ + n] = g * acc[i][j][r] + res;
            }
        }
    }
}

// ---------------------------------------------------------------------------
extern "C" void kernel_launch(void* const* d_in, const int* in_sizes, int n_in,
                              void* d_out, int out_size, void* d_ws, size_t ws_size,
                              hipStream_t stream)
{
    const float* x1       = (const float*)d_in[0];
    const float* x2       = (const float*)d_in[1];
    const float* se_w1    = (const float*)d_in[2];
    const float* se_w2    = (const float*)d_in[3];
    const float* conv_w   = (const float*)d_in[4];
    const float* bn_gamma = (const float*)d_in[5];
    const float* bn_beta  = (const float*)d_in[6];
    const float* bn_mean  = (const float*)d_in[7];
    const float* bn_var   = (const float*)d_in[8];
    const float* gamma    = (const float*)d_in[9];
    float* out = (float*)d_out;

    // Workspace layout — total 135,266,304 B (proven footprint)
    char* ws = (char*)d_ws;
    float* zp   = (float*)(ws);                      //       0 +   512 B (zero page)
    float* se   = (float*)(ws + 8192);               //    8192 +     8 KB
    f16*   Ph   = (f16*)  (ws + 16384);              //   16384 +   256 KB
    f16*   wt   = (f16*)  (ws + 278528);             //  278528 +   576 KB
    f16*   xs   = (f16*)  (ws + 1048576);            // 1 MB    +    64 MB
    float* simp = (float*)(ws + 1048576);            // aliases xs (post-conv)
    f16*   yh   = (f16*)  (ws + 68157440);           //         +    32 MB
    float* avgp = (float*)(ws + 68157440);           // aliases yh (pre-conv), 1 MB
    f16*   yt   = (f16*)  (ws + 101711872);          //         +    32 MB

    prep_kernel<<<dim3(H_, B_), 256, 0, stream>>>(x1, x2, conv_w, avgp, xs, wt, zp);
    se_mlp_kernel<<<dim3(B_), 256, 0, stream>>>(avgp, se_w1, se_w2, se);

    hipFuncSetAttribute((const void*)conv_mfma_big,
        hipFuncAttributeMaxDynamicSharedMemorySize, SMEM_BYTES);
    conv_mfma_big<<<dim3(2, H_ / 2, B_), 256, SMEM_BYTES, stream>>>(
        xs, wt, se, (const f16*)zp, bn_gamma, bn_beta, bn_mean, bn_var, yh, yt);

    sim_mfma_kernel<<<dim3(NS_, B_), 512, 0, stream>>>(yh, simp);
    softmax_kernel<<<dim3(B_ * C_), 128, 0, stream>>>(simp, Ph);
    feat_mfma_kernel<<<dim3(HW_ / 128, B_), 256, 0, stream>>>(Ph, yt, yh, gamma, out);
}